// Round 9
// baseline (160.465 us; speedup 1.0000x reference)
//
#include <hip/hip_runtime.h>
#include <math.h>

#define B_    2
#define C_    64
#define N_    20000
#define K_    16
#define COUT_ 64
#define NCH   4                        // channel chunks (16 ch each)
#define TN1   64
#define NB1   ((N_ + TN1 - 1) / TN1)   // 313
#define TN2   32
#define NB2   (N_ / TN2)               // 625 (exact, no tail)

typedef unsigned int   u32;
typedef unsigned short u16;

static __device__ __forceinline__ u16 f2bf(float f) {
    union { float f; u32 u; } v; v.f = f;
    u32 r = (v.u + 0x7FFFu + ((v.u >> 16) & 1u)) >> 16;  // RNE
    return (u16)r;
}
static __device__ __forceinline__ float uasf(u32 u) {
    union { u32 u; float f; } v; v.u = u; return v.f;
}

// ---------------------------------------------------------------------------
// Stage 1: z = (W1-W2)x + b, y = W2 x -> bf16 tables, CHUNK-MAJOR layout
// [b][chunk=o>>4][n][o&15] so stage 2 can process one 2.56 MB chunk-pair at
// a time (L2-resident per XCD). Core GEMM unchanged (scratch-proof: weights
// in LDS, 8 NAMED float4 accumulators; rounds 3/4 proved per-thread arrays
// go to scratch).
// ---------------------------------------------------------------------------
__global__ __launch_bounds__(256)
void stage1(const float* __restrict__ x, const float* __restrict__ W,
            const float* __restrict__ bias,
            u16* __restrict__ zbuf, u16* __restrict__ ybuf) {
    __shared__ float xt[64][68];    // [c][n_local], rows 16B-aligned
    __shared__ float wc[64][130];   // [c][2*o+{0,1}] = (w1-w2, w2)

    const int bi   = blockIdx.x;
    const int b    = bi / NB1;
    const int n0   = (bi % NB1) * TN1;
    const int t    = threadIdx.x;
    const int lane = t & 63;        // = output channel o
    const int w    = t >> 6;

    // ---- stage weights (coalesced): 64o x 64c ----
    #pragma unroll
    for (int r = 0; r < 16; ++r) {
        int flat = r * 256 + t;
        int o = flat >> 6, c = flat & 63;
        float w1 = W[o * 128 + c];
        float w2 = W[o * 128 + 64 + c];
        wc[c][2 * o]     = w1 - w2;
        wc[c][2 * o + 1] = w2;
    }
    // ---- stage x tile [c][n] via float4 (coalesced) ----
    const float* xb = x + (size_t)b * C_ * N_;
    #pragma unroll
    for (int r = 0; r < 4; ++r) {
        int flat = r * 256 + t;
        int c = flat >> 4, ng = (flat & 15) * 4;
        int n = n0 + ng;
        float4 v;
        if (n + 3 < N_) {
            v = *(const float4*)&xb[c * N_ + n];
        } else {
            v.x = (n     < N_) ? xb[c * N_ + n    ] : 0.0f;
            v.y = (n + 1 < N_) ? xb[c * N_ + n + 1] : 0.0f;
            v.z = (n + 2 < N_) ? xb[c * N_ + n + 2] : 0.0f;
            v.w = (n + 3 < N_) ? xb[c * N_ + n + 3] : 0.0f;
        }
        *(float4*)&xt[c][ng] = v;
    }
    const float bo = bias[lane];
    __syncthreads();

    // ---- wave computes 16 nodes, all accumulators NAMED float4 ----
    const int nb = w * 16;
    float4 z0 = {bo,bo,bo,bo}, z1 = z0, z2 = z0, z3 = z0;
    float4 y0 = {0,0,0,0},     y1 = y0, y2 = y0, y3 = y0;

#define FMA4(ZR, YR, XV) \
    ZR.x = fmaf(wv.x, XV.x, ZR.x);  YR.x = fmaf(wv.y, XV.x, YR.x); \
    ZR.y = fmaf(wv.x, XV.y, ZR.y);  YR.y = fmaf(wv.y, XV.y, YR.y); \
    ZR.z = fmaf(wv.x, XV.z, ZR.z);  YR.z = fmaf(wv.y, XV.z, YR.z); \
    ZR.w = fmaf(wv.x, XV.w, ZR.w);  YR.w = fmaf(wv.y, XV.w, YR.w);

    #pragma unroll 2
    for (int c = 0; c < 64; ++c) {
        float2 wv = *(const float2*)&wc[c][2 * lane];   // conflict-free
        float4 xa = *(const float4*)&xt[c][nb];         // uniform broadcasts
        float4 xv1 = *(const float4*)&xt[c][nb + 4];
        float4 xv2 = *(const float4*)&xt[c][nb + 8];
        float4 xv3 = *(const float4*)&xt[c][nb + 12];
        FMA4(z0, y0, xa)
        FMA4(z1, y1, xv1)
        FMA4(z2, y2, xv2)
        FMA4(z3, y3, xv3)
    }
#undef FMA4

    {
        // chunk-major store: [b][o>>4][n][o&15]
        const size_t cbase = ((size_t)b * NCH + (lane >> 4)) * N_;
        const int    ci    = lane & 15;
        auto st = [&](int i, float zv, float yv) {
            int n = n0 + nb + i;
            if (n < N_) {
                size_t off = (cbase + n) * 16 + ci;
                zbuf[off] = f2bf(zv);
                ybuf[off] = f2bf(yv);
            }
        };
        st(0,  z0.x, y0.x); st(1,  z0.y, y0.y); st(2,  z0.z, y0.z); st(3,  z0.w, y0.w);
        st(4,  z1.x, y1.x); st(5,  z1.y, y1.y); st(6,  z1.z, y1.z); st(7,  z1.w, y1.w);
        st(8,  z2.x, y2.x); st(9,  z2.y, y2.y); st(10, z2.z, y2.z); st(11, z2.w, y2.w);
        st(12, z3.x, y3.x); st(13, z3.y, y3.y); st(14, z3.z, y3.z); st(15, z3.w, y3.w);
    }
}

// ---------------------------------------------------------------------------
// Stage 2, channel-chunked: grid = (chunk major, batch, node-tile). While
// chunk c runs, each XCD's gather working set is one 2.56 MB chunk-pair ->
// L2-resident. Per block: 32 nodes x 16 k x 32 B (z) + 32 B (y).
// lane = (nl = t>>3, kh = (t>>1)&3, cq = t&1): 4 serial k's per lane
// (round-6-proven chain depth), shfl_xor strides 2,4 merge kh.
// Phase A (edge prep from ei/pos) redone per chunk -- L2-hot, cheap.
// ---------------------------------------------------------------------------
__global__ __launch_bounds__(256)
void stage2(const int* __restrict__ ei, const float* __restrict__ pos,
            const u16* __restrict__ zbuf, const u16* __restrict__ ybuf,
            float* __restrict__ out) {
    __shared__ uint2 esl[TN2][17];       // 512 edge records
    __shared__ float tile[TN2][20];      // [node][16ch], row 80 B (16B-mult)

    const int bi = blockIdx.x;
    const int c  = bi / (B_ * NB2);      // chunk 0..3 (chunk-major dispatch)
    const int r  = bi % (B_ * NB2);
    const int b  = r / NB2;
    const int n0 = (r % NB2) * TN2;
    const int t  = threadIdx.x;
    const int nl = t >> 3;               // node 0..31
    const int kh = (t >> 1) & 3;         // k group 0..3
    const int cq = t & 1;                // 16 B half of the 32 B chunk row

    // ---- Phase A: 512 edges, 2 per thread ----
    {
        const int*   e0 = ei + (size_t)b * N_ * K_;
        const int*   e1 = ei + ((size_t)B_ + b) * N_ * K_;
        const float* pb = pos + (size_t)b * 3 * N_;
        #pragma unroll
        for (int r2 = 0; r2 < 2; ++r2) {
            int li  = r2 * 256 + t;                  // 0..511 within tile
            int idx = n0 * K_ + li;                  // coalesced
            int i0 = e0[idx], i1 = e1[idx];
            float dx = pb[i0]          - pb[i1];
            float dy = pb[N_ + i0]     - pb[N_ + i1];
            float dz = pb[2 * N_ + i0] - pb[2 * N_ + i1];
            float dis = sqrtf(dx * dx + dy * dy + dz * dz);
            float s = 2.0f / (1.0f + __expf(dis));   // 2*sigmoid(-dis)
            esl[li >> 4][li & 15] = make_uint2((u32)i0 | ((u32)i1 << 16),
                                               __float_as_uint(s));
        }
    }
    __syncthreads();

    const u16* zb = zbuf + ((size_t)b * NCH + c) * N_ * 16;
    const u16* yb = ybuf + ((size_t)b * NCH + c) * N_ * 16;

    float4 ma = {0,0,0,0}, mb = {0,0,0,0};   // this lane's 8 channel maxima

#define COMB(ZW, YW, MLO, MHI) { \
    float zl = uasf((ZW) << 16), zh = uasf((ZW) & 0xFFFF0000u); \
    float yl = uasf((YW) << 16), yh = uasf((YW) & 0xFFFF0000u); \
    MLO = fmaxf(MLO, fmaxf(zl + yl, 0.0f) * s); \
    MHI = fmaxf(MHI, fmaxf(zh + yh, 0.0f) * s); }

    #pragma unroll
    for (int i = 0; i < 4; ++i) {
        int   k = 4 * i + kh;
        uint2 e = esl[nl][k];
        int   i0 = (int)(e.x & 0xFFFFu);
        int   i1 = (int)(e.x >> 16);
        float s  = uasf(e.y);
        uint4 z4 = *(const uint4*)(zb + (size_t)i1 * 16 + cq * 8);  // 16 B
        uint4 y4 = *(const uint4*)(yb + (size_t)i0 * 16 + cq * 8);
        COMB(z4.x, y4.x, ma.x, ma.y)
        COMB(z4.y, y4.y, ma.z, ma.w)
        COMB(z4.z, y4.z, mb.x, mb.y)
        COMB(z4.w, y4.w, mb.z, mb.w)
    }
#undef COMB

    // ---- merge the 4 k-groups: xor lane bits 1,2 (cq bit 0 intact) ----
#define R4(V, ST) \
    V.x = fmaxf(V.x, __shfl_xor(V.x, ST)); \
    V.y = fmaxf(V.y, __shfl_xor(V.y, ST)); \
    V.z = fmaxf(V.z, __shfl_xor(V.z, ST)); \
    V.w = fmaxf(V.w, __shfl_xor(V.w, ST));
    R4(ma, 2)  R4(mb, 2)
    R4(ma, 4)  R4(mb, 4)
#undef R4

    if (kh == 0) {                       // lane owns (nl, cq): 8 channels
        *(float4*)&tile[nl][cq * 8]     = ma;
        *(float4*)&tile[nl][cq * 8 + 4] = mb;
    }
    __syncthreads();

    // ---- coalesced writeback: 16 ch x 32 nodes, nontemporal ----
    #pragma unroll
    for (int r2 = 0; r2 < 2; ++r2) {
        int flat = r2 * 256 + t;
        int o = flat >> 5, n2 = flat & 31;
        __builtin_nontemporal_store(tile[n2][o],
            &out[((size_t)b * COUT_ + c * 16 + o) * N_ + n0 + n2]);
    }
}

// ---------------------------------------------------------------------------
extern "C" void kernel_launch(void* const* d_in, const int* in_sizes, int n_in,
                              void* d_out, int out_size, void* d_ws, size_t ws_size,
                              hipStream_t stream) {
    const float* x    = (const float*)d_in[0];   // [B, C, N, 1]
    const int*   ei   = (const int*)  d_in[1];   // [2, B, N, K]
    const float* pos  = (const float*)d_in[2];   // [B, 3, N, 1]
    const float* W    = (const float*)d_in[3];   // [COUT, 2C]
    const float* bias = (const float*)d_in[4];   // [COUT]
    float*       out  = (float*)d_out;           // [B, COUT, N, 1]

    const size_t tabElems = (size_t)B_ * NCH * N_ * 16;      // 2.56M u16
    u16* zbuf = (u16*)d_ws;                                  // 5.12 MB
    u16* ybuf = zbuf + tabElems;                             // 5.12 MB

    hipLaunchKernelGGL(stage1, dim3(B_ * NB1), dim3(256), 0, stream,
                       x, W, bias, zbuf, ybuf);
    hipLaunchKernelGGL(stage2, dim3(NCH * B_ * NB2), dim3(256), 0, stream,
                       ei, pos, zbuf, ybuf, out);
}